// Round 13
// baseline (78.209 us; speedup 1.0000x reference)
//
#include <hip/hip_runtime.h>
#include <hip/hip_bf16.h>

// B=16, Ci=16, Co=16, H=W=24, hidden=64.
// kt:    K[dy47][dxi][o][i] bf16; dy47 = dy+23 in [0,47), dxi = dx+24 in [0,49).
//        dxi stride = 256 shorts (r9-11 bug: 512 -> OOB fault; fixed r12).
// vpad2: bf16 [y'=40][x'=40][b=16][i=16], y'=h+8, x'=w+8, zero halo.
// r13: combine kernel removed. prep also inits out=bias; conv LDS-reduces over
//   tq then atomicAdd's s*(1/576) into out (7 octet-blocks accumulate there).

typedef __attribute__((ext_vector_type(8))) short bf16x8;
typedef __attribute__((ext_vector_type(4))) float f32x4;

#define KT_ELEMS (47*49*256)          // 589,568 bf16
#define VPAD2_ELEMS (40*40*256)       // 409,600 bf16
#define NROWS (47*49)                 // 2303 MLP rows
#define NPOS 576                      // 24*24 output positions
#define OUT_ELEMS (256*NPOS)          // 147,456 floats
#define NOCT 7                        // dy octets (7*4 = 28 >= 27)
#define PREP_BUILD_BLOCKS 288         // ceil(2303/8)
#define PREP_PAD_BLOCKS (VPAD2_ELEMS/256)   // 1600
#define PREP_OUT_BLOCKS (OUT_ELEMS/256)     // 576

// ---------------- Kernel 1: prep = build kt + pad v + init out --------------
__launch_bounds__(256)
__global__ void prep(const float* __restrict__ v,
                     const float* __restrict__ w1, const float* __restrict__ b1,
                     const float* __restrict__ w2, const float* __restrict__ b2,
                     const float* __restrict__ bias,
                     __hip_bfloat16* __restrict__ kt, __hip_bfloat16* __restrict__ vpad,
                     float* __restrict__ out)
{
    const int tid = threadIdx.x;
    const int bid = blockIdx.x;

    if (bid >= PREP_BUILD_BLOCKS + PREP_PAD_BLOCKS) {
        // ---- out init: out[c2*576 + p] = bias[c2 & 15] ----
        int idx = (bid - PREP_BUILD_BLOCKS - PREP_PAD_BLOCKS)*256 + tid;
        out[idx] = bias[(idx / NPOS) & 15];
        return;
    }

    if (bid >= PREP_BUILD_BLOCKS) {
        // ---- pad part: vpad2[y][x][b][i] ----
        int idx = (bid - PREP_BUILD_BLOCKS)*256 + tid;
        int i = idx & 15;
        int b = (idx >> 4) & 15;
        int s = idx >> 8;             // y*40 + x
        int x = s % 40;
        int y = s / 40;
        int h = y - 8, w = x - 8;
        float val = 0.0f;
        if (h >= 0 && h < 24 && w >= 0 && w < 24)
            val = v[((b*16 + i)*24 + h)*24 + w];
        vpad[idx] = __float2bfloat16(val);
        return;
    }

    // ---- build part: 8 rows of the [2303 x 256] K GEMM per block ----
    __shared__ float ty_s[47];
    __shared__ float tx_s[49];
    __shared__ float hid_s[8][64];
    const int r0 = bid * 8;

    if (tid < 47)               ty_s[tid]      = tanhf((float)(tid - 23) * (1.0f/6.0f));
    if (tid >= 64 && tid < 113) tx_s[tid - 64] = tanhf((float)(tid - 64 - 24) * (1.0f/6.0f));
    __syncthreads();

    #pragma unroll
    for (int k = 0; k < 2; ++k) {
        int idx = k*256 + tid;
        int rr  = idx >> 6;
        int j   = idx & 63;
        int r   = r0 + rr;
        if (r >= NROWS) r = NROWS - 1;
        int dy47 = r / 49;
        int dxi  = r % 49;
        float x = ty_s[dy47]*w1[2*j] + tx_s[dxi]*w1[2*j+1] + b1[j];
        hid_s[rr][j] = 0.5f*x*(1.0f + erff(x*0.70710678118f));
    }
    __syncthreads();

    const int c = tid;
    float acc[8];
    const float bb = b2[c];
    #pragma unroll
    for (int r = 0; r < 8; ++r) acc[r] = bb;

    const float4* w2v = (const float4*)w2;
    #pragma unroll
    for (int jv = 0; jv < 16; ++jv) {
        float4 wv = w2v[c*16 + jv];
        #pragma unroll
        for (int e = 0; e < 4; ++e) {
            float we = ((const float*)&wv)[e];
            int j = jv*4 + e;
            #pragma unroll
            for (int r = 0; r < 8; ++r)
                acc[r] += hid_s[r][j] * we;
        }
    }

    #pragma unroll
    for (int rr = 0; rr < 8; ++rr) {
        int r = r0 + rr;
        if (r >= NROWS) break;
        kt[r*256 + c] = __float2bfloat16(acc[rr]);
    }
}

// ---------------- Kernel 2: MFMA correlation + atomic accumulate ------------
// 8 waves: wv = tq + 4*hhh. Wave: one dy (t = oct*4+tq), rows h0+hhh*2+{0,1},
// cols w0..w0+3, 12 dxp steps. A slides (2 fresh/step), B 2 fresh/step.
// A(ww,dxp): dxi = 24 - w0 - ww + 2*dxp + d; dxi stride = 256 shorts.
// Range: min dxi = 1, max = 47 < 49. Two-phase LDS reduce over tq, then
// atomicAdd(out, s * 1/576).
__launch_bounds__(512)
__global__ void conv_part(const __hip_bfloat16* __restrict__ kt_,
                          const __hip_bfloat16* __restrict__ vpad_,
                          float* __restrict__ out)
{
    __shared__ f32x4 red[8][4][64];   // [src wave][ww][lane], 32 KB
    const short* kt = (const short*)kt_;
    const short* vp = (const short*)vpad_;

    const int wt  = blockIdx.x;       // 0..5  -> w0 = wt*4
    const int hg  = blockIdx.y;       // 0..5  -> h0 = hg*4
    const int oct = blockIdx.z;       // 0..6
    const int w0  = wt * 4;
    const int h0  = hg * 4;

    const int tid  = threadIdx.x;
    const int lane = tid & 63;
    const int wv   = tid >> 6;        // 0..7
    const int tq   = wv & 3;
    const int hhh  = wv >> 2;         // h-pair of this wave
    const int n    = lane & 15;       // A: o row; B: b col
    const int g    = lane >> 4;       // k-group
    const int d    = g >> 1;          // dx sub-offset within pair
    const int ih   = (g & 1) * 8;     // i-half

    const int t = oct*4 + tq;         // dy index; dy = t - h0 - 3, valid t<27

    f32x4 acc[2][4];
    #pragma unroll
    for (int hh = 0; hh < 2; ++hh)
        #pragma unroll
        for (int ww = 0; ww < 4; ++ww) acc[hh][ww] = (f32x4){0.f,0.f,0.f,0.f};

    if (t < 27) {
        const int dy47 = t - h0 + 20;                       // in [0,46]
        // base: dxi(ww=0,dxp=0) = 24 - w0 + d
        const short* apb = kt + ((long)(dy47*49 + (24 - w0 + d)))*256 + n*16 + ih;
        // B(hh,dxp): y' = t+hhh*2+hh+5, x' = 8+2dxp+d
        const short* bpb = vp + ((long)((t + hhh*2 + 5)*40 + (8 + d)))*256 + n*16 + ih;

        bf16x8 av[4];
        av[0] = *(const bf16x8*)(apb);            // ww=0: dxi base
        av[1] = *(const bf16x8*)(apb - 256);      // ww=1: dxi-1
        av[2] = *(const bf16x8*)(apb - 512);      // ww=2: dxi-2
        av[3] = *(const bf16x8*)(apb - 768);      // ww=3: dxi-3

        #pragma unroll
        for (int dxp = 0; dxp < 12; ++dxp) {
            bf16x8 bv0 = *(const bf16x8*)(bpb +         dxp*512);   // x' += 2/dxp
            bf16x8 bv1 = *(const bf16x8*)(bpb + 10240 + dxp*512);   // +1 y' row
            #pragma unroll
            for (int ww = 0; ww < 4; ++ww) {
                acc[0][ww] = __builtin_amdgcn_mfma_f32_16x16x32_bf16(av[ww], bv0, acc[0][ww], 0, 0, 0);
                acc[1][ww] = __builtin_amdgcn_mfma_f32_16x16x32_bf16(av[ww], bv1, acc[1][ww], 0, 0, 0);
            }
            if (dxp < 11) {
                av[2] = av[0];                    // A(2,dxp+1) = A(0,dxp)
                av[3] = av[1];                    // A(3,dxp+1) = A(1,dxp)
                av[0] = *(const bf16x8*)(apb + (2*dxp + 2)*256);    // dxi(0,dxp+1)
                av[1] = *(const bf16x8*)(apb + (2*dxp + 1)*256);    // dxi(1,dxp+1)
            }
        }
    }

    // Two-phase reduce (32 KB): phase hh stores acc[hh][*], then wave wv
    // (hhh2 = wv>>2, ww2 = wv&3) atomically accumulates row h = h0+hhh2*2+hh.
    const float sc = 1.0f/576.0f;
    #pragma unroll
    for (int hh = 0; hh < 2; ++hh) {
        if (hh) __syncthreads();                  // protect red reuse
        #pragma unroll
        for (int ww = 0; ww < 4; ++ww) red[wv][ww][lane] = acc[hh][ww];
        __syncthreads();

        const int hhh2 = wv >> 2;
        const int ww2  = wv & 3;
        f32x4 s = red[4*hhh2 + 0][ww2][lane];
        s += red[4*hhh2 + 1][ww2][lane];
        s += red[4*hhh2 + 2][ww2][lane];
        s += red[4*hhh2 + 3][ww2][lane];

        const int h = h0 + hhh2*2 + hh;
        const int w = w0 + ww2;
        const int p = h*24 + w;
        // out[c2*576 + p], c2 = n*16 + g*4 + e
        float* dst = out + (size_t)(n*16 + g*4)*NPOS + p;
        #pragma unroll
        for (int e = 0; e < 4; ++e)
            atomicAdd(dst + (size_t)e*NPOS, s[e]*sc);
    }
}

extern "C" void kernel_launch(void* const* d_in, const int* in_sizes, int n_in,
                              void* d_out, int out_size, void* d_ws, size_t ws_size,
                              hipStream_t stream)
{
    const float* v    = (const float*)d_in[0];
    const float* w1   = (const float*)d_in[1];
    const float* b1   = (const float*)d_in[2];
    const float* w2   = (const float*)d_in[3];
    const float* b2   = (const float*)d_in[4];
    const float* bias = (const float*)d_in[5];
    float* out = (float*)d_out;

    char* ws = (char*)d_ws;
    __hip_bfloat16* kt   = (__hip_bfloat16*)ws;                          // 1,179,136 B
    __hip_bfloat16* vpad = (__hip_bfloat16*)(ws + (size_t)KT_ELEMS*2);   //   819,200 B

    prep<<<dim3(PREP_BUILD_BLOCKS + PREP_PAD_BLOCKS + PREP_OUT_BLOCKS),
           dim3(256), 0, stream>>>(v, w1, b1, w2, b2, bias, kt, vpad, out);
    conv_part<<<dim3(6, 6, NOCT), dim3(512), 0, stream>>>(kt, vpad, out);
}